// Round 1
// baseline (108.649 us; speedup 1.0000x reference)
//
#include <hip/hip_runtime.h>

// Problem constants (fixed by the reference harness)
#define NF    4
#define NLOC  16384
#define NNEI  128
#define NALL  32768
#define TMASK_N 81   // (ntypes+1)^2 with ntypes=8

// Each thread handles 4 consecutive neighbors of one (f, i) row.
// nlist loaded as int4 (coalesced 16B/lane), out stored as float4.
__global__ void __launch_bounds__(256) pair_exclude_mask_kernel(
    const int* __restrict__ nlist,
    const int* __restrict__ atype_ext,
    const float* __restrict__ type_mask,
    const int* __restrict__ ntypes_p,
    float* __restrict__ out)
{
    __shared__ float smask[TMASK_N];
    if (threadIdx.x < TMASK_N) smask[threadIdx.x] = type_mask[threadIdx.x];
    __syncthreads();

    const int ntypes = ntypes_p[0];          // 8; broadcast L1 read

    // linear index over groups of 4 neighbors
    const long long total4 = (long long)NF * NLOC * NNEI / 4;
    long long g = (long long)blockIdx.x * blockDim.x + threadIdx.x;
    if (g >= total4) return;

    const long long e = g * 4;               // element index
    const int f  = (int)(e / ((long long)NLOC * NNEI));
    const int r  = (int)(e - (long long)f * NLOC * NNEI);
    const int i  = r / NNEI;                 // local atom

    const int ti = atype_ext[f * NALL + i] * (ntypes + 1);  // broadcast across 32 lanes

    const int4 nl = *reinterpret_cast<const int4*>(nlist + e);
    const int* ae = atype_ext + (long long)f * NALL;

    float4 m;
    {
        int tj = (nl.x == -1) ? ntypes : ae[nl.x];
        m.x = smask[ti + tj];
    }
    {
        int tj = (nl.y == -1) ? ntypes : ae[nl.y];
        m.y = smask[ti + tj];
    }
    {
        int tj = (nl.z == -1) ? ntypes : ae[nl.z];
        m.z = smask[ti + tj];
    }
    {
        int tj = (nl.w == -1) ? ntypes : ae[nl.w];
        m.w = smask[ti + tj];
    }

    *reinterpret_cast<float4*>(out + e) = m;
}

extern "C" void kernel_launch(void* const* d_in, const int* in_sizes, int n_in,
                              void* d_out, int out_size, void* d_ws, size_t ws_size,
                              hipStream_t stream) {
    const int*   nlist     = (const int*)d_in[0];
    const int*   atype_ext = (const int*)d_in[1];
    const float* type_mask = (const float*)d_in[2];
    const int*   ntypes_p  = (const int*)d_in[3];
    float*       out       = (float*)d_out;

    const long long total4 = (long long)NF * NLOC * NNEI / 4;  // 2,097,152
    const int block = 256;
    const int grid  = (int)((total4 + block - 1) / block);     // 8192

    pair_exclude_mask_kernel<<<grid, block, 0, stream>>>(
        nlist, atype_ext, type_mask, ntypes_p, out);
}

// Round 2
// 91.208 us; speedup vs baseline: 1.1912x; 1.1912x over previous
//
#include <hip/hip_runtime.h>

// Problem constants (fixed by the reference harness)
#define NF    4
#define NLOC  16384
#define NNEI  128
#define NALL  32768
#define TMASK_LDS 96          // >= (ntypes+1)^2 = 81

#define ELEMS_PER_FRAME (NLOC * NNEI)          // 2,097,152
#define Q4_PER_FRAME    (ELEMS_PER_FRAME / 4)  // 524,288 float4 groups
#define BLOCKS_PER_FRAME 256
#define THREADS 256
#define ITERS (Q4_PER_FRAME / (BLOCKS_PER_FRAME * THREADS))  // 8

// ---------------------------------------------------------------------------
// Pre-pass: compress atype_ext (int32, values 0..ntypes-1) into a per-frame
// uint8 table in d_ws. 131072 elements total -> 32768 threads x int4->uchar4.
// ---------------------------------------------------------------------------
__global__ void __launch_bounds__(256) build_type_table(
    const int* __restrict__ atype_ext,
    unsigned char* __restrict__ ttab)
{
    const int t = blockIdx.x * blockDim.x + threadIdx.x;   // 0 .. 32767
    const int4 v = reinterpret_cast<const int4*>(atype_ext)[t];
    uchar4 b;
    b.x = (unsigned char)v.x;
    b.y = (unsigned char)v.y;
    b.z = (unsigned char)v.z;
    b.w = (unsigned char)v.w;
    reinterpret_cast<uchar4*>(ttab)[t] = b;
}

// ---------------------------------------------------------------------------
// Main kernel: per block, stage one frame's 32KB uint8 type table + the mask
// table into LDS; stream nlist as int4, gather types from LDS, store float4.
// ---------------------------------------------------------------------------
__global__ void __launch_bounds__(THREADS) pair_exclude_mask_kernel(
    const int* __restrict__ nlist,
    const unsigned char* __restrict__ ttab,   // [NF][NALL] uint8 in d_ws
    const float* __restrict__ type_mask,
    const int* __restrict__ ntypes_p,
    float* __restrict__ out)
{
    __shared__ unsigned char stt[NALL];       // 32 KB
    __shared__ float smask[TMASK_LDS];

    const int f = blockIdx.x / BLOCKS_PER_FRAME;
    const int b = blockIdx.x % BLOCKS_PER_FRAME;

    // stage frame type table (2048 x uint4) + mask table
    {
        const uint4* src = reinterpret_cast<const uint4*>(ttab + (size_t)f * NALL);
        uint4* dst = reinterpret_cast<uint4*>(stt);
        #pragma unroll
        for (int k = 0; k < NALL / 16 / THREADS; ++k)           // 8 iters
            dst[threadIdx.x + k * THREADS] = src[threadIdx.x + k * THREADS];
        if (threadIdx.x < 81) smask[threadIdx.x] = type_mask[threadIdx.x];
    }
    __syncthreads();

    const int ntypes = ntypes_p[0];           // 8
    const int np1 = ntypes + 1;               // 9

    const int* nl_base = nlist + (size_t)f * ELEMS_PER_FRAME;
    float* out_base = out + (size_t)f * ELEMS_PER_FRAME;
    const int q0 = b * (THREADS * ITERS);     // contiguous chunk of float4 groups

    #pragma unroll
    for (int it = 0; it < ITERS; ++it) {
        const int q = q0 + it * THREADS + threadIdx.x;
        const int4 nl = reinterpret_cast<const int4*>(nl_base)[q];
        const int e = q * 4;
        const int i = e >> 7;                 // element / NNEI
        const int ti = (int)stt[i] * np1;

        float4 m;
        {
            const int tj = (nl.x == -1) ? ntypes : (int)stt[nl.x];
            m.x = smask[ti + tj];
        }
        {
            const int tj = (nl.y == -1) ? ntypes : (int)stt[nl.y];
            m.y = smask[ti + tj];
        }
        {
            const int tj = (nl.z == -1) ? ntypes : (int)stt[nl.z];
            m.z = smask[ti + tj];
        }
        {
            const int tj = (nl.w == -1) ? ntypes : (int)stt[nl.w];
            m.w = smask[ti + tj];
        }
        reinterpret_cast<float4*>(out_base)[q] = m;
    }
}

extern "C" void kernel_launch(void* const* d_in, const int* in_sizes, int n_in,
                              void* d_out, int out_size, void* d_ws, size_t ws_size,
                              hipStream_t stream) {
    const int*   nlist     = (const int*)d_in[0];
    const int*   atype_ext = (const int*)d_in[1];
    const float* type_mask = (const float*)d_in[2];
    const int*   ntypes_p  = (const int*)d_in[3];
    float*       out       = (float*)d_out;
    unsigned char* ttab    = (unsigned char*)d_ws;   // NF*NALL = 128 KB

    // pre-pass: 131072 int32 -> uint8, 32768 threads
    build_type_table<<<(NF * NALL / 4) / 256, 256, 0, stream>>>(atype_ext, ttab);

    pair_exclude_mask_kernel<<<NF * BLOCKS_PER_FRAME, THREADS, 0, stream>>>(
        nlist, ttab, type_mask, ntypes_p, out);
}